// Round 5
// baseline (443.984 us; speedup 1.0000x reference)
//
#include <hip/hip_runtime.h>
#include <hip/hip_bf16.h>

// Per-token-group (G=128) fp8-range quantization:
//   y = clip(x / (max(amax,1e-4)/448), -448, 448)  [fp32], scale = amax/448.
//   d_out = [ y (MN fp32) | scale (MN/128 fp32) ].
//
// V5 (full-line stores) — RESUBMISSION: round-4 bench failed with a GPU
// acquisition timeout; this kernel was never measured. Theory unchanged:
// V2/V4 stalled at ~2.5 TB/s; the store pattern had lane l owning elems
// l*8..l*8+7, so each float4 store wrote 16 B in every 32 B (half-line
// sectors -> 2x L2 line transactions on the 256 MB write stream). New lane
// mapping: lane l owns elems l*4..l*4+3 and 64+l*4..64+l*4+3 of its group:
//   * loads:  2 x 8 B per lane, each instr cluster-contiguous (full lines)
//   * stores: 2 x 16 B per lane, unit-stride across the 16-lane cluster
//             (256 B contiguous per instr = 4 full 64 B lines)
// Also: 32-bit offsets (buffers < 2 GB) and v_rcp_f32 for 448/amax (absmax
// margin 2.0; rcp error ~1e-4) to shorten the serial chain.
// Kept verbatim: dtype vote, 16-lane __shfl_xor amax reduce, MLP=4 hoist,
// exact-division grid.

static constexpr float FP8_MAX_F  = 448.0f;
static constexpr float AMAX_FLOOR = 1e-4f;

typedef float floatx4 __attribute__((ext_vector_type(4)));

__device__ __forceinline__ void decode4(const uint2 w, float v[4])
{
    v[0] = __uint_as_float((w.x & 0xffffu) << 16);  // low bf16
    v[1] = __uint_as_float(w.x & 0xffff0000u);      // high bf16
    v[2] = __uint_as_float((w.y & 0xffffu) << 16);
    v[3] = __uint_as_float(w.y & 0xffff0000u);
}

// v[0..3] = elems l*4..l*4+3, v[4..7] = elems 64+l*4..64+l*4+3 of group (e0>>7)
__device__ __forceinline__ void process_store(const float v[8],
                                              unsigned e0,           // gid*128 + lane16*4
                                              float* __restrict__ y,
                                              float* __restrict__ scale,
                                              int lane16)
{
    // pairwise abs-max tree over 8 (short dep chain), then 16-lane butterfly
    float m01 = fmaxf(fabsf(v[0]), fabsf(v[1]));
    float m23 = fmaxf(fabsf(v[2]), fabsf(v[3]));
    float m45 = fmaxf(fabsf(v[4]), fabsf(v[5]));
    float m67 = fmaxf(fabsf(v[6]), fabsf(v[7]));
    float m = fmaxf(fmaxf(m01, m23), fmaxf(m45, m67));
    m = fmaxf(m, __shfl_xor(m, 1));
    m = fmaxf(m, __shfl_xor(m, 2));
    m = fmaxf(m, __shfl_xor(m, 4));
    m = fmaxf(m, __shfl_xor(m, 8));

    const float amax = fmaxf(m, AMAX_FLOOR);
    const float s    = amax * (1.0f / FP8_MAX_F);
    // fast reciprocal: 1-ulp v_rcp_f32; |err| on y ~ 448*2^-23 ~ 1e-4,
    // well inside the absmax=2.0 margin the exact-div version passed with.
    const float inv  = FP8_MAX_F * __builtin_amdgcn_rcpf(amax);

    floatx4 oA, oB;
    oA.x = fminf(fmaxf(v[0] * inv, -FP8_MAX_F), FP8_MAX_F);
    oA.y = fminf(fmaxf(v[1] * inv, -FP8_MAX_F), FP8_MAX_F);
    oA.z = fminf(fmaxf(v[2] * inv, -FP8_MAX_F), FP8_MAX_F);
    oA.w = fminf(fmaxf(v[3] * inv, -FP8_MAX_F), FP8_MAX_F);
    oB.x = fminf(fmaxf(v[4] * inv, -FP8_MAX_F), FP8_MAX_F);
    oB.y = fminf(fmaxf(v[5] * inv, -FP8_MAX_F), FP8_MAX_F);
    oB.z = fminf(fmaxf(v[6] * inv, -FP8_MAX_F), FP8_MAX_F);
    oB.w = fminf(fmaxf(v[7] * inv, -FP8_MAX_F), FP8_MAX_F);

    // full-line stores: 16 lanes x 16 B unit-stride = 256 B contiguous each
    *(floatx4*)(y + e0)       = oA;
    *(floatx4*)(y + e0 + 64u) = oB;

    if (lane16 == 0) scale[e0 >> 7] = s;
}

__global__ __launch_bounds__(256) void quant_v5_kernel(
    const void* __restrict__ xraw,
    float* __restrict__ y,
    float* __restrict__ scale,
    int iters)                 // tiles per block (grid divides tiles exactly)
{
    __shared__ int flag_s;

    // --- input dtype vote (same 64 words for every block; L3-resident) ---
    if (threadIdx.x < 64) {
        const unsigned int w  = ((const unsigned int*)xraw)[threadIdx.x];
        const bool lo_nonzero = (w & 0xffffu) != 0u;   // true => packed bf16
        unsigned long long mm = __ballot(lo_nonzero);
        if (threadIdx.x == 0) flag_s = (__popcll(mm) >= 32) ? 1 : 0;
    }
    __syncthreads();
    const bool in_bf16 = (flag_s != 0);

    const int lane16 = threadIdx.x & 15;   // position within the 16-lane cluster
    const int gsub   = threadIdx.x >> 4;   // which of the 16 groups this block-iter
    const unsigned tstride = gridDim.x;

    unsigned tile = blockIdx.x;
    int it = 0;

    if (in_bf16) {
        const __hip_bfloat16* xb = (const __hip_bfloat16*)xraw;
        // ---- main loop: 4 tiles, all 8 loads issued before first use ----
        for (; it + 4 <= iters; it += 4) {
            unsigned e0[4];
            uint2 ra[4], rb[4];
#pragma unroll
            for (int u = 0; u < 4; ++u) {
                const unsigned gid = (tile + (unsigned)u * tstride) * 16u + gsub;
                e0[u] = gid * 128u + (unsigned)lane16 * 4u;
                ra[u] = *(const uint2*)(xb + e0[u]);          // elems l*4..+3
                rb[u] = *(const uint2*)(xb + e0[u] + 64u);    // elems 64+l*4..+3
            }
#pragma unroll
            for (int u = 0; u < 4; ++u) {
                float v[8];
                decode4(ra[u], v);
                decode4(rb[u], v + 4);
                process_store(v, e0[u], y, scale, lane16);
            }
            tile += 4u * tstride;
        }
        // ---- remainder ----
        for (; it < iters; ++it, tile += tstride) {
            const unsigned gid = tile * 16u + gsub;
            const unsigned e0  = gid * 128u + (unsigned)lane16 * 4u;
            float v[8];
            decode4(*(const uint2*)(xb + e0), v);
            decode4(*(const uint2*)(xb + e0 + 64u), v + 4);
            process_store(v, e0, y, scale, lane16);
        }
    } else {
        const float* xf = (const float*)xraw;
        // ---- fp32 fallback (safety net; same structure) ----
        for (; it + 4 <= iters; it += 4) {
            unsigned e0[4];
            floatx4 ra[4], rb[4];
#pragma unroll
            for (int u = 0; u < 4; ++u) {
                const unsigned gid = (tile + (unsigned)u * tstride) * 16u + gsub;
                e0[u] = gid * 128u + (unsigned)lane16 * 4u;
                ra[u] = *(const floatx4*)(xf + e0[u]);
                rb[u] = *(const floatx4*)(xf + e0[u] + 64u);
            }
#pragma unroll
            for (int u = 0; u < 4; ++u) {
                float v[8] = {ra[u].x, ra[u].y, ra[u].z, ra[u].w,
                              rb[u].x, rb[u].y, rb[u].z, rb[u].w};
                process_store(v, e0[u], y, scale, lane16);
            }
            tile += 4u * tstride;
        }
        for (; it < iters; ++it, tile += tstride) {
            const unsigned gid = tile * 16u + gsub;
            const unsigned e0  = gid * 128u + (unsigned)lane16 * 4u;
            const floatx4 a = *(const floatx4*)(xf + e0);
            const floatx4 b = *(const floatx4*)(xf + e0 + 64u);
            float v[8] = {a.x, a.y, a.z, a.w, b.x, b.y, b.z, b.w};
            process_store(v, e0, y, scale, lane16);
        }
    }
}

extern "C" void kernel_launch(void* const* d_in, const int* in_sizes, int n_in,
                              void* d_out, int out_size, void* d_ws, size_t ws_size,
                              hipStream_t stream) {
    const long long MN = (long long)in_sizes[0];   // M*N elements, divisible by 128
    const long long n_groups = MN / 128;

    float* y     = (float*)d_out;
    float* scale = y + MN;                         // outputs concatenated: y then scale

    const int threads = 256;                       // 4 waves; 16 groups per iteration
    const long long tiles = (n_groups + 15) / 16;

    // Largest grid <= 2048 dividing tiles exactly (bench shape: 32768 tiles
    // -> 2048 blocks x 16 iters). No per-iter bounds check needed.
    long long blocks = tiles < 2048 ? tiles : 2048;
    while (tiles % blocks != 0) --blocks;          // terminates at 1 worst-case
    const int iters = (int)(tiles / blocks);

    quant_v5_kernel<<<(int)blocks, threads, 0, stream>>>(d_in[0], y, scale, iters);
}

// Round 6
// 426.724 us; speedup vs baseline: 1.0404x; 1.0404x over previous
//
#include <hip/hip_runtime.h>
#include <hip/hip_bf16.h>

// Per-token-group (G=128) fp8-range quantization:
//   y = clip(x / (max(amax,1e-4)/448), -448, 448)  [fp32], scale = amax/448.
//   d_out = [ y (MN fp32) | scale (MN/128 fp32) ].
//
// V6 (self-balancing grid): measured ordering across rounds was
//   V2 (simple loop) 436.2 < V4 (MLP hoist) 441.8 < V5 (full-line stores) 444.0
// i.e. every manual restructuring after V2 was neutral-or-worse -> revert to
// the V2 memory pattern verbatim (16 B bf16 load per lane, two float4
// stores, 16-lane __shfl_xor reduce). ONE structural change: drop the
// 2048-block persistent grid (iters=16 grid-stride; OccupancyPercent was
// stuck at 63.7% despite resources permitting 100% -> residency/imbalance
// suspect) in favor of one tile per block, full grid (32768 blocks), which
// the command processor load-balances like the 6.4 TB/s fill kernels do.
// Kept from V5 (measured-passed): v_rcp_f32 for 448/amax.

static constexpr float FP8_MAX_F  = 448.0f;
static constexpr float AMAX_FLOOR = 1e-4f;

typedef float floatx4 __attribute__((ext_vector_type(4)));

__global__ __launch_bounds__(256) void quant_v6_kernel(
    const void* __restrict__ xraw,
    float* __restrict__ y,
    float* __restrict__ scale,
    long long n_groups)
{
    __shared__ int flag_s;

    // --- input dtype vote (same 64 words for every block; L2/L3-resident) ---
    if (threadIdx.x < 64) {
        const unsigned int w  = ((const unsigned int*)xraw)[threadIdx.x];
        const bool lo_nonzero = (w & 0xffffu) != 0u;   // true => packed bf16
        unsigned long long m  = __ballot(lo_nonzero);
        if (threadIdx.x == 0) flag_s = (__popcll(m) >= 32) ? 1 : 0;
    }
    __syncthreads();
    const bool in_bf16 = (flag_s != 0);

    const int lane16 = threadIdx.x & 15;   // position within the group (8 elems each)
    const int gsub   = threadIdx.x >> 4;   // which of this block's 16 groups

    const long long gid = (long long)blockIdx.x * 16 + gsub;
    if (gid >= n_groups) return;           // full grid; exact for bench shape

    const long long base = gid * 128 + (long long)lane16 * 8;  // element offset

    float v[8];
    if (in_bf16) {
        // 16 B = 8 bf16. base*2 bytes is 16B-aligned (base % 8 == 0).
        const int4 raw = *(const int4*)((const __hip_bfloat16*)xraw + base);
        const unsigned int* wp = (const unsigned int*)&raw;
#pragma unroll
        for (int i = 0; i < 4; ++i) {
            const unsigned int w = wp[i];
            v[2 * i]     = __uint_as_float((w & 0xffffu) << 16);  // low bf16
            v[2 * i + 1] = __uint_as_float(w & 0xffff0000u);      // high bf16
        }
    } else {
        const floatx4 a = ((const floatx4*)((const float*)xraw + base))[0];
        const floatx4 b = ((const floatx4*)((const float*)xraw + base))[1];
        v[0] = a.x; v[1] = a.y; v[2] = a.z; v[3] = a.w;
        v[4] = b.x; v[5] = b.y; v[6] = b.z; v[7] = b.w;
    }

    // --- per-lane abs-max over 8 (pairwise tree), then 16-lane butterfly ---
    float m01 = fmaxf(fabsf(v[0]), fabsf(v[1]));
    float m23 = fmaxf(fabsf(v[2]), fabsf(v[3]));
    float m45 = fmaxf(fabsf(v[4]), fabsf(v[5]));
    float m67 = fmaxf(fabsf(v[6]), fabsf(v[7]));
    float m = fmaxf(fmaxf(m01, m23), fmaxf(m45, m67));
    m = fmaxf(m, __shfl_xor(m, 1));
    m = fmaxf(m, __shfl_xor(m, 2));
    m = fmaxf(m, __shfl_xor(m, 4));
    m = fmaxf(m, __shfl_xor(m, 8));

    const float amax = fmaxf(m, AMAX_FLOOR);
    const float s    = amax * (1.0f / FP8_MAX_F);
    // 1-ulp v_rcp_f32: |err| on y ~ 448*2^-23 ~ 5e-5 rel, passed in V5.
    const float inv  = FP8_MAX_F * __builtin_amdgcn_rcpf(amax);

    floatx4 o0, o1;
    o0.x = fminf(fmaxf(v[0] * inv, -FP8_MAX_F), FP8_MAX_F);
    o0.y = fminf(fmaxf(v[1] * inv, -FP8_MAX_F), FP8_MAX_F);
    o0.z = fminf(fmaxf(v[2] * inv, -FP8_MAX_F), FP8_MAX_F);
    o0.w = fminf(fmaxf(v[3] * inv, -FP8_MAX_F), FP8_MAX_F);
    o1.x = fminf(fmaxf(v[4] * inv, -FP8_MAX_F), FP8_MAX_F);
    o1.y = fminf(fmaxf(v[5] * inv, -FP8_MAX_F), FP8_MAX_F);
    o1.z = fminf(fmaxf(v[6] * inv, -FP8_MAX_F), FP8_MAX_F);
    o1.w = fminf(fmaxf(v[7] * inv, -FP8_MAX_F), FP8_MAX_F);

    ((floatx4*)(y + base))[0] = o0;
    ((floatx4*)(y + base))[1] = o1;

    // 16 scale writes per block are contiguous (one 64 B line)
    if (lane16 == 0) scale[gid] = s;
}

extern "C" void kernel_launch(void* const* d_in, const int* in_sizes, int n_in,
                              void* d_out, int out_size, void* d_ws, size_t ws_size,
                              hipStream_t stream) {
    const long long MN = (long long)in_sizes[0];   // M*N elements, divisible by 128
    const long long n_groups = MN / 128;

    float* y     = (float*)d_out;
    float* scale = y + MN;                         // outputs concatenated: y then scale

    const int threads = 256;                       // 16 groups per block
    const long long blocks = (n_groups + 15) / 16; // full grid, self-balancing
                                                   // (bench shape: 32768 blocks)

    quant_v6_kernel<<<(int)blocks, threads, 0, stream>>>(d_in[0], y, scale,
                                                         n_groups);
}